// Round 1
// baseline (2977.480 us; speedup 1.0000x reference)
//
#include <hip/hip_runtime.h>

#define N_NODES 100000
#define N_EDGES 1600000
#define D 128

// ---- K1: count in-degree of dst nodes (edge part only; +1 self-loop added later)
__global__ void count_deg(const int* __restrict__ dst, int* __restrict__ deg) {
    int e = blockIdx.x * blockDim.x + threadIdx.x;
    if (e < N_EDGES) atomicAdd(&deg[dst[e]], 1);
}

// ---- K2: dinv[n] = rsqrt(deg[n] + 1)   (self-loop makes deg >= 1, no zero case)
__global__ void compute_dinv(const int* __restrict__ deg, float* __restrict__ dinv) {
    int n = blockIdx.x * blockDim.x + threadIdx.x;
    if (n < N_NODES) dinv[n] = rsqrtf((float)deg[n] + 1.0f);
}

// ---- K3: agg[n][:] = x[n][:] * dinv[n]^2   (self-loop term; also initializes agg)
__global__ void init_agg(const float4* __restrict__ x4, const float* __restrict__ dinv,
                         float4* __restrict__ agg4) {
    int i = blockIdx.x * blockDim.x + threadIdx.x;  // over N_NODES * 32 float4s
    if (i < N_NODES * (D / 4)) {
        int n = i >> 5;                  // 32 float4 per node row
        float s = dinv[n];
        s *= s;
        float4 v = x4[i];
        v.x *= s; v.y *= s; v.z *= s; v.w *= s;
        agg4[i] = v;
    }
}

// ---- K4: edge scatter. 32 threads per edge, each does one float4 gather + 4 atomicAdds.
__global__ void scatter_edges(const int* __restrict__ ei, const float* __restrict__ dinv,
                              const float4* __restrict__ x4, float* __restrict__ agg) {
    long long t = (long long)blockIdx.x * blockDim.x + threadIdx.x;
    int e = (int)(t >> 5);
    int c = (int)(t & 31);
    if (e >= N_EDGES) return;
    int s  = ei[e];
    int d2 = ei[N_EDGES + e];
    float w = dinv[s] * dinv[d2];
    float4 v = x4[(size_t)s * 32 + c];
    float* dp = &agg[(size_t)d2 * D + c * 4];
    atomicAdd(dp + 0, v.x * w);
    atomicAdd(dp + 1, v.y * w);
    atomicAdd(dp + 2, v.z * w);
    atomicAdd(dp + 3, v.w * w);
}

// ---- K5: out = relu(agg @ W + b).  16 rows per block, 256 threads.
// thread (tr = tid>>5 in 0..7, tc = tid&31): rows {tr, tr+8}, cols [4*tc, 4*tc+4)
__global__ __launch_bounds__(256) void gemm_bias_relu(
        const float* __restrict__ agg, const float4* __restrict__ W4,
        const float4* __restrict__ b4, float4* __restrict__ out4) {
    __shared__ float xs[16][D];  // 8 KB
    const int r0 = blockIdx.x * 16;
    const int tid = threadIdx.x;

    // stage 16 rows (512 float4) of agg into LDS
    const float4* a4 = (const float4*)(agg + (size_t)r0 * D);
    float4* xs4 = (float4*)xs;
    xs4[tid]       = a4[tid];
    xs4[tid + 256] = a4[tid + 256];
    __syncthreads();

    const int tc = tid & 31;
    const int tr = tid >> 5;
    float4 acc0 = {0.f, 0.f, 0.f, 0.f};
    float4 acc1 = {0.f, 0.f, 0.f, 0.f};
    #pragma unroll 8
    for (int k = 0; k < D; ++k) {
        float4 w = W4[k * 32 + tc];
        float xa = xs[tr][k];
        float xb = xs[tr + 8][k];
        acc0.x = fmaf(xa, w.x, acc0.x); acc0.y = fmaf(xa, w.y, acc0.y);
        acc0.z = fmaf(xa, w.z, acc0.z); acc0.w = fmaf(xa, w.w, acc0.w);
        acc1.x = fmaf(xb, w.x, acc1.x); acc1.y = fmaf(xb, w.y, acc1.y);
        acc1.z = fmaf(xb, w.z, acc1.z); acc1.w = fmaf(xb, w.w, acc1.w);
    }
    float4 bb = b4[tc];
    acc0.x = fmaxf(acc0.x + bb.x, 0.f); acc0.y = fmaxf(acc0.y + bb.y, 0.f);
    acc0.z = fmaxf(acc0.z + bb.z, 0.f); acc0.w = fmaxf(acc0.w + bb.w, 0.f);
    acc1.x = fmaxf(acc1.x + bb.x, 0.f); acc1.y = fmaxf(acc1.y + bb.y, 0.f);
    acc1.z = fmaxf(acc1.z + bb.z, 0.f); acc1.w = fmaxf(acc1.w + bb.w, 0.f);
    out4[(size_t)(r0 + tr) * 32 + tc]     = acc0;
    out4[(size_t)(r0 + tr + 8) * 32 + tc] = acc1;
}

extern "C" void kernel_launch(void* const* d_in, const int* in_sizes, int n_in,
                              void* d_out, int out_size, void* d_ws, size_t ws_size,
                              hipStream_t stream) {
    const float* x  = (const float*)d_in[0];
    // d_in[1] = x_0 (unused by the reference)
    const float* W  = (const float*)d_in[2];
    const float* b  = (const float*)d_in[3];
    const int*   ei = (const int*)d_in[4];   // [2, N_EDGES]: src then dst
    float* out = (float*)d_out;

    // workspace layout
    float* agg  = (float*)d_ws;                         // N_NODES * D floats (51.2 MB)
    int*   deg  = (int*)(agg + (size_t)N_NODES * D);    // N_NODES ints
    float* dinv = (float*)(deg + N_NODES);              // N_NODES floats

    hipMemsetAsync(deg, 0, N_NODES * sizeof(int), stream);

    count_deg<<<(N_EDGES + 255) / 256, 256, 0, stream>>>(ei + N_EDGES, deg);
    compute_dinv<<<(N_NODES + 255) / 256, 256, 0, stream>>>(deg, dinv);
    init_agg<<<(N_NODES * (D / 4) + 255) / 256, 256, 0, stream>>>(
        (const float4*)x, dinv, (float4*)agg);
    scatter_edges<<<(int)(((long long)N_EDGES * 32 + 255) / 256), 256, 0, stream>>>(
        ei, dinv, (const float4*)x, agg);
    gemm_bias_relu<<<N_NODES / 16, 256, 0, stream>>>(
        agg, (const float4*)W, (const float4*)b, (float4*)out);
}

// Round 2
// 503.537 us; speedup vs baseline: 5.9131x; 5.9131x over previous
//
#include <hip/hip_runtime.h>

#define N_NODES 100000
#define N_EDGES 1600000
#define D 128
#define SCAN_CHUNK 1024
#define N_SCAN_BLOCKS ((N_NODES + SCAN_CHUNK - 1) / SCAN_CHUNK)  // 98

// ---- K1: count in-degree of dst nodes (edge part only; +1 self-loop in dinv)
__global__ void count_deg(const int* __restrict__ dst, int* __restrict__ deg) {
    int e = blockIdx.x * blockDim.x + threadIdx.x;
    if (e < N_EDGES) atomicAdd(&deg[dst[e]], 1);
}

// ---- K2: dinv[n] = rsqrt(deg[n] + 1)
__global__ void compute_dinv(const int* __restrict__ deg, float* __restrict__ dinv) {
    int n = blockIdx.x * blockDim.x + threadIdx.x;
    if (n < N_NODES) dinv[n] = rsqrtf((float)deg[n] + 1.0f);
}

__device__ inline int wave_incl_scan(int v, int lane) {
    #pragma unroll
    for (int off = 1; off < 64; off <<= 1) {
        int y = __shfl_up(v, off);
        if (lane >= off) v += y;
    }
    return v;
}

// ---- K3a: per-1024-chunk sums
__global__ __launch_bounds__(256) void block_sums(const int* __restrict__ deg,
                                                  int* __restrict__ blocksum) {
    __shared__ int wsum[4];
    int t = threadIdx.x, lane = t & 63, w = t >> 6;
    int base_i = blockIdx.x * SCAN_CHUNK + t * 4;
    int s = 0;
    #pragma unroll
    for (int j = 0; j < 4; ++j) { int i = base_i + j; if (i < N_NODES) s += deg[i]; }
    #pragma unroll
    for (int off = 32; off; off >>= 1) s += __shfl_down(s, off);
    if (lane == 0) wsum[w] = s;
    __syncthreads();
    if (t == 0) blocksum[blockIdx.x] = wsum[0] + wsum[1] + wsum[2] + wsum[3];
}

// ---- K3b: exclusive scan of the 98 chunk sums (serial, tiny)
__global__ void scan_partials(int* __restrict__ blocksum) {
    if (threadIdx.x == 0 && blockIdx.x == 0) {
        int acc = 0;
        for (int i = 0; i < N_SCAN_BLOCKS; ++i) {
            int v = blocksum[i]; blocksum[i] = acc; acc += v;
        }
    }
}

// ---- K3c: exclusive scan within each chunk + chunk base -> row_start
__global__ __launch_bounds__(256) void scan_write(const int* __restrict__ deg,
                                                  const int* __restrict__ blockbase,
                                                  int* __restrict__ row_start) {
    __shared__ int wsum[4];
    int t = threadIdx.x, lane = t & 63, w = t >> 6;
    int base_i = blockIdx.x * SCAN_CHUNK + t * 4;
    int v[4]; int s = 0;
    #pragma unroll
    for (int j = 0; j < 4; ++j) {
        int i = base_i + j;
        v[j] = (i < N_NODES) ? deg[i] : 0;
        s += v[j];
    }
    int incl = wave_incl_scan(s, lane);
    int ex = incl - s;
    if (lane == 63) wsum[w] = incl;
    __syncthreads();
    int wbase = 0;
    for (int j = 0; j < w; ++j) wbase += wsum[j];
    int off = blockbase[blockIdx.x] + wbase + ex;
    #pragma unroll
    for (int j = 0; j < 4; ++j) {
        int i = base_i + j;
        if (i < N_NODES) row_start[i] = off;
        off += v[j];
    }
}

// ---- K4: bucket-fill CSR: csr[pos] = {src, weight} for each edge, grouped by dst
__global__ void fill_csr(const int* __restrict__ ei, const float* __restrict__ dinv,
                         const int* __restrict__ row_start, int* __restrict__ cursor,
                         int2* __restrict__ csr) {
    int e = blockIdx.x * blockDim.x + threadIdx.x;
    if (e >= N_EDGES) return;
    int s = ei[e];
    int d = ei[N_EDGES + e];
    int pos = row_start[d] + atomicAdd(&cursor[d], 1);
    float w = dinv[s] * dinv[d];
    csr[pos] = make_int2(s, __float_as_int(w));
}

// ---- K5: gather. 32 lanes per node, 8 nodes per 256-block. No atomics.
__global__ __launch_bounds__(256) void gather(const int2* __restrict__ csr,
                                              const int* __restrict__ row_start,
                                              const int* __restrict__ deg,
                                              const float* __restrict__ dinv,
                                              const float4* __restrict__ x4,
                                              float4* __restrict__ agg4) {
    int tid = threadIdx.x;
    int c = tid & 31;
    int n = blockIdx.x * 8 + (tid >> 5);
    if (n >= N_NODES) return;
    float di = dinv[n];
    float sw = di * di;
    float4 acc = x4[(size_t)n * 32 + c];   // self-loop term
    acc.x *= sw; acc.y *= sw; acc.z *= sw; acc.w *= sw;
    int rs = row_start[n], dg = deg[n];
    for (int base = 0; base < dg; base += 32) {
        int m = min(32, dg - base);
        int2 pr = make_int2(0, 0);
        if (c < m) pr = csr[rs + base + c];     // 256 B coalesced per chunk
        for (int j = 0; j < m; ++j) {
            int   s = __shfl(pr.x, j, 32);
            float w = __int_as_float(__shfl(pr.y, j, 32));
            float4 v = x4[(size_t)s * 32 + c];  // 128 B per group, L3-resident
            acc.x = fmaf(w, v.x, acc.x); acc.y = fmaf(w, v.y, acc.y);
            acc.z = fmaf(w, v.z, acc.z); acc.w = fmaf(w, v.w, acc.w);
        }
    }
    agg4[(size_t)n * 32 + c] = acc;
}

// ---- K6: out = relu(agg @ W + b). 16 rows per block, 256 threads.
__global__ __launch_bounds__(256) void gemm_bias_relu(
        const float* __restrict__ agg, const float4* __restrict__ W4,
        const float4* __restrict__ b4, float4* __restrict__ out4) {
    __shared__ float xs[16][D];  // 8 KB
    const int r0 = blockIdx.x * 16;
    const int tid = threadIdx.x;

    const float4* a4 = (const float4*)(agg + (size_t)r0 * D);
    float4* xs4 = (float4*)xs;
    xs4[tid]       = a4[tid];
    xs4[tid + 256] = a4[tid + 256];
    __syncthreads();

    const int tc = tid & 31;
    const int tr = tid >> 5;
    float4 acc0 = {0.f, 0.f, 0.f, 0.f};
    float4 acc1 = {0.f, 0.f, 0.f, 0.f};
    #pragma unroll 8
    for (int k = 0; k < D; ++k) {
        float4 w = W4[k * 32 + tc];
        float xa = xs[tr][k];
        float xb = xs[tr + 8][k];
        acc0.x = fmaf(xa, w.x, acc0.x); acc0.y = fmaf(xa, w.y, acc0.y);
        acc0.z = fmaf(xa, w.z, acc0.z); acc0.w = fmaf(xa, w.w, acc0.w);
        acc1.x = fmaf(xb, w.x, acc1.x); acc1.y = fmaf(xb, w.y, acc1.y);
        acc1.z = fmaf(xb, w.z, acc1.z); acc1.w = fmaf(xb, w.w, acc1.w);
    }
    float4 bb = b4[tc];
    acc0.x = fmaxf(acc0.x + bb.x, 0.f); acc0.y = fmaxf(acc0.y + bb.y, 0.f);
    acc0.z = fmaxf(acc0.z + bb.z, 0.f); acc0.w = fmaxf(acc0.w + bb.w, 0.f);
    acc1.x = fmaxf(acc1.x + bb.x, 0.f); acc1.y = fmaxf(acc1.y + bb.y, 0.f);
    acc1.z = fmaxf(acc1.z + bb.z, 0.f); acc1.w = fmaxf(acc1.w + bb.w, 0.f);
    out4[(size_t)(r0 + tr) * 32 + tc]     = acc0;
    out4[(size_t)(r0 + tr + 8) * 32 + tc] = acc1;
}

extern "C" void kernel_launch(void* const* d_in, const int* in_sizes, int n_in,
                              void* d_out, int out_size, void* d_ws, size_t ws_size,
                              hipStream_t stream) {
    const float* x  = (const float*)d_in[0];
    // d_in[1] = x_0 (unused by the reference)
    const float* W  = (const float*)d_in[2];
    const float* b  = (const float*)d_in[3];
    const int*   ei = (const int*)d_in[4];   // [2, N_EDGES]: src then dst
    float* out = (float*)d_out;

    // workspace layout (~65.6 MB)
    float* agg       = (float*)d_ws;                          // N*D floats (51.2 MB)
    int*   deg       = (int*)(agg + (size_t)N_NODES * D);     // N ints
    int*   cursor    = deg + N_NODES;                         // N ints (adjacent: one memset)
    float* dinv      = (float*)(cursor + N_NODES);            // N floats
    int*   row_start = (int*)(dinv + N_NODES);                // N ints
    int*   blocksum  = row_start + N_NODES;                   // 98 ints
    int2*  csr       = (int2*)(blocksum + 128);               // E int2 (12.8 MB)

    hipMemsetAsync(deg, 0, 2 * N_NODES * sizeof(int), stream);  // deg + cursor

    count_deg<<<(N_EDGES + 255) / 256, 256, 0, stream>>>(ei + N_EDGES, deg);
    compute_dinv<<<(N_NODES + 255) / 256, 256, 0, stream>>>(deg, dinv);
    block_sums<<<N_SCAN_BLOCKS, 256, 0, stream>>>(deg, blocksum);
    scan_partials<<<1, 64, 0, stream>>>(blocksum);
    scan_write<<<N_SCAN_BLOCKS, 256, 0, stream>>>(deg, blocksum, row_start);
    fill_csr<<<(N_EDGES + 255) / 256, 256, 0, stream>>>(ei, dinv, row_start, cursor, csr);
    gather<<<(N_NODES + 7) / 8, 256, 0, stream>>>(csr, row_start, deg, dinv,
                                                  (const float4*)x, (float4*)agg);
    gemm_bias_relu<<<N_NODES / 16, 256, 0, stream>>>(
        agg, (const float4*)W, (const float4*)b, (float4*)out);
}

// Round 3
// 445.838 us; speedup vs baseline: 6.6784x; 1.1294x over previous
//
#include <hip/hip_runtime.h>

#define N_NODES 100000
#define N_EDGES 1600000
#define D 128
#define SCAN_CHUNK 1024
#define N_SCAN_BLOCKS ((N_NODES + SCAN_CHUNK - 1) / SCAN_CHUNK)  // 98

__device__ inline float bf2f(unsigned short u) {
    return __uint_as_float(((unsigned int)u) << 16);
}
__device__ inline unsigned short f2bf(float f) {  // round-to-nearest-even
    unsigned int u = __float_as_uint(f);
    unsigned int r = u + 0x7FFF + ((u >> 16) & 1);
    return (unsigned short)(r >> 16);
}

// ---- K1: count in-degree of dst nodes (edge part only; +1 self-loop in dinv)
__global__ void count_deg(const int* __restrict__ dst, int* __restrict__ deg) {
    int e = blockIdx.x * blockDim.x + threadIdx.x;
    if (e < N_EDGES) atomicAdd(&deg[dst[e]], 1);
}

__device__ inline int wave_incl_scan(int v, int lane) {
    #pragma unroll
    for (int off = 1; off < 64; off <<= 1) {
        int y = __shfl_up(v, off);
        if (lane >= off) v += y;
    }
    return v;
}

// ---- K2: per-1024-chunk sums of deg, fused with dinv = rsqrt(deg+1)
__global__ __launch_bounds__(256) void block_sums_dinv(const int* __restrict__ deg,
                                                       int* __restrict__ blocksum,
                                                       float* __restrict__ dinv) {
    __shared__ int wsum[4];
    int t = threadIdx.x, lane = t & 63, w = t >> 6;
    int base_i = blockIdx.x * SCAN_CHUNK + t * 4;
    int s = 0;
    #pragma unroll
    for (int j = 0; j < 4; ++j) {
        int i = base_i + j;
        if (i < N_NODES) {
            int dv = deg[i];
            s += dv;
            dinv[i] = rsqrtf((float)dv + 1.0f);
        }
    }
    #pragma unroll
    for (int off = 32; off; off >>= 1) s += __shfl_down(s, off);
    if (lane == 0) wsum[w] = s;
    __syncthreads();
    if (t == 0) blocksum[blockIdx.x] = wsum[0] + wsum[1] + wsum[2] + wsum[3];
}

// ---- K3: parallel exclusive scan of the 98 chunk sums (one block)
__global__ __launch_bounds__(128) void scan_partials(int* __restrict__ bs) {
    __shared__ int w0sum;
    int t = threadIdx.x, lane = t & 63, w = t >> 6;
    int v = (t < N_SCAN_BLOCKS) ? bs[t] : 0;
    int incl = wave_incl_scan(v, lane);
    if (w == 0 && lane == 63) w0sum = incl;
    __syncthreads();
    int ex = incl - v + (w ? w0sum : 0);
    if (t < N_SCAN_BLOCKS) bs[t] = ex;
}

// ---- K4: exclusive scan within each chunk + chunk base -> row_start
__global__ __launch_bounds__(256) void scan_write(const int* __restrict__ deg,
                                                  const int* __restrict__ blockbase,
                                                  int* __restrict__ row_start) {
    __shared__ int wsum[4];
    int t = threadIdx.x, lane = t & 63, w = t >> 6;
    int base_i = blockIdx.x * SCAN_CHUNK + t * 4;
    int v[4]; int s = 0;
    #pragma unroll
    for (int j = 0; j < 4; ++j) {
        int i = base_i + j;
        v[j] = (i < N_NODES) ? deg[i] : 0;
        s += v[j];
    }
    int incl = wave_incl_scan(s, lane);
    int ex = incl - s;
    if (lane == 63) wsum[w] = incl;
    __syncthreads();
    int wbase = 0;
    for (int j = 0; j < w; ++j) wbase += wsum[j];
    int off = blockbase[blockIdx.x] + wbase + ex;
    #pragma unroll
    for (int j = 0; j < 4; ++j) {
        int i = base_i + j;
        if (i < N_NODES) row_start[i] = off;
        off += v[j];
    }
}

// ---- K5: bucket-fill CSR (src index only; norm folded into h')
__global__ void fill_csr(const int* __restrict__ ei, const int* __restrict__ row_start,
                         int* __restrict__ cursor, int* __restrict__ csr) {
    int e = blockIdx.x * blockDim.x + threadIdx.x;
    if (e >= N_EDGES) return;
    int s = ei[e];
    int d = ei[N_EDGES + e];
    int pos = row_start[d] + atomicAdd(&cursor[d], 1);
    csr[pos] = s;
}

// ---- K6: h'[r] = dinv[r] * (x[r] @ W), stored bf16. 16 rows/block, 256 threads.
__global__ __launch_bounds__(256) void gemm_h(
        const float* __restrict__ x, const float4* __restrict__ W4,
        const float* __restrict__ dinv, ushort4* __restrict__ h4) {
    __shared__ float xs[16][D];  // 8 KB
    const int r0 = blockIdx.x * 16;
    const int tid = threadIdx.x;

    const float4* a4 = (const float4*)(x + (size_t)r0 * D);
    float4* xs4 = (float4*)xs;
    xs4[tid]       = a4[tid];
    xs4[tid + 256] = a4[tid + 256];
    __syncthreads();

    const int tc = tid & 31;
    const int tr = tid >> 5;
    float4 acc0 = {0.f, 0.f, 0.f, 0.f};
    float4 acc1 = {0.f, 0.f, 0.f, 0.f};
    #pragma unroll 8
    for (int k = 0; k < D; ++k) {
        float4 w = W4[k * 32 + tc];
        float xa = xs[tr][k];
        float xb = xs[tr + 8][k];
        acc0.x = fmaf(xa, w.x, acc0.x); acc0.y = fmaf(xa, w.y, acc0.y);
        acc0.z = fmaf(xa, w.z, acc0.z); acc0.w = fmaf(xa, w.w, acc0.w);
        acc1.x = fmaf(xb, w.x, acc1.x); acc1.y = fmaf(xb, w.y, acc1.y);
        acc1.z = fmaf(xb, w.z, acc1.z); acc1.w = fmaf(xb, w.w, acc1.w);
    }
    float d0 = dinv[r0 + tr];
    float d1 = dinv[r0 + tr + 8];
    h4[(size_t)(r0 + tr) * 32 + tc] =
        make_ushort4(f2bf(acc0.x * d0), f2bf(acc0.y * d0), f2bf(acc0.z * d0), f2bf(acc0.w * d0));
    h4[(size_t)(r0 + tr + 8) * 32 + tc] =
        make_ushort4(f2bf(acc1.x * d1), f2bf(acc1.y * d1), f2bf(acc1.z * d1), f2bf(acc1.w * d1));
}

// ---- K7: out[n] = relu(dinv[n] * (h'[n] + sum_in h'[s]) + b). 32 lanes/node.
__global__ __launch_bounds__(256) void gather_out(const int* __restrict__ csr,
                                                  const int* __restrict__ row_start,
                                                  const int* __restrict__ deg,
                                                  const float* __restrict__ dinv,
                                                  const ushort4* __restrict__ h4,
                                                  const float4* __restrict__ b4,
                                                  float4* __restrict__ out4) {
    int tid = threadIdx.x;
    int c = tid & 31;
    int n = blockIdx.x * 8 + (tid >> 5);
    if (n >= N_NODES) return;
    ushort4 hv = h4[(size_t)n * 32 + c];   // self-loop term
    float4 acc = {bf2f(hv.x), bf2f(hv.y), bf2f(hv.z), bf2f(hv.w)};
    int rs = row_start[n], dg = deg[n];
    for (int base = 0; base < dg; base += 32) {
        int m = min(32, dg - base);
        int src = 0;
        if (c < m) src = csr[rs + base + c];    // 128 B coalesced per chunk
        for (int j = 0; j < m; ++j) {
            int s = __shfl(src, j, 32);
            ushort4 v = h4[(size_t)s * 32 + c]; // 256 B/row, L2/L3-resident
            acc.x += bf2f(v.x); acc.y += bf2f(v.y);
            acc.z += bf2f(v.z); acc.w += bf2f(v.w);
        }
    }
    float di = dinv[n];
    float4 bb = b4[c];
    float4 o;
    o.x = fmaxf(fmaf(di, acc.x, bb.x), 0.f);
    o.y = fmaxf(fmaf(di, acc.y, bb.y), 0.f);
    o.z = fmaxf(fmaf(di, acc.z, bb.z), 0.f);
    o.w = fmaxf(fmaf(di, acc.w, bb.w), 0.f);
    out4[(size_t)n * 32 + c] = o;
}

extern "C" void kernel_launch(void* const* d_in, const int* in_sizes, int n_in,
                              void* d_out, int out_size, void* d_ws, size_t ws_size,
                              hipStream_t stream) {
    const float* x  = (const float*)d_in[0];
    // d_in[1] = x_0 (unused by the reference)
    const float* W  = (const float*)d_in[2];
    const float* b  = (const float*)d_in[3];
    const int*   ei = (const int*)d_in[4];   // [2, N_EDGES]: src then dst
    float* out = (float*)d_out;

    // workspace layout (~34 MB)
    ushort4* h4      = (ushort4*)d_ws;                         // N*D bf16 (25.6 MB)
    int*   deg       = (int*)((unsigned short*)d_ws + (size_t)N_NODES * D);
    int*   cursor    = deg + N_NODES;
    float* dinv      = (float*)(cursor + N_NODES);
    int*   row_start = (int*)(dinv + N_NODES);
    int*   blocksum  = row_start + N_NODES;                    // 98 ints
    int*   csr       = blocksum + 128;                         // E ints (6.4 MB)

    hipMemsetAsync(deg, 0, 2 * N_NODES * sizeof(int), stream);  // deg + cursor

    count_deg<<<(N_EDGES + 255) / 256, 256, 0, stream>>>(ei + N_EDGES, deg);
    block_sums_dinv<<<N_SCAN_BLOCKS, 256, 0, stream>>>(deg, blocksum, dinv);
    scan_partials<<<1, 128, 0, stream>>>(blocksum);
    scan_write<<<N_SCAN_BLOCKS, 256, 0, stream>>>(deg, blocksum, row_start);
    fill_csr<<<(N_EDGES + 255) / 256, 256, 0, stream>>>(ei, row_start, cursor, csr);
    gemm_h<<<N_NODES / 16, 256, 0, stream>>>(x, (const float4*)W, dinv, h4);
    gather_out<<<(N_NODES + 7) / 8, 256, 0, stream>>>(csr, row_start, deg, dinv, h4,
                                                      (const float4*)b, (float4*)out);
}

// Round 5
// 381.334 us; speedup vs baseline: 7.8081x; 1.1692x over previous
//
#include <hip/hip_runtime.h>

#define N_NODES 100000
#define N_EDGES 1600000
#define D 128
#define SCAN_CHUNK 1024
#define N_SCAN_BLOCKS ((N_NODES + SCAN_CHUNK - 1) / SCAN_CHUNK)  // 98

typedef __attribute__((ext_vector_type(8))) short bf16x8;
typedef __attribute__((ext_vector_type(4))) float f32x4;

__device__ inline float bf2f(unsigned short u) {
    return __uint_as_float(((unsigned int)u) << 16);
}
__device__ inline unsigned short f2bf(float f) {  // round-to-nearest-even
    unsigned int u = __float_as_uint(f);
    unsigned int r = u + 0x7FFF + ((u >> 16) & 1);
    return (unsigned short)(r >> 16);
}

// ---- K1: count in-degree of dst nodes (edge part only; +1 self-loop in dinv)
__global__ void count_deg(const int* __restrict__ dst, int* __restrict__ deg) {
    int e = blockIdx.x * blockDim.x + threadIdx.x;
    if (e < N_EDGES) atomicAdd(&deg[dst[e]], 1);
}

__device__ inline int wave_incl_scan(int v, int lane) {
    #pragma unroll
    for (int off = 1; off < 64; off <<= 1) {
        int y = __shfl_up(v, off);
        if (lane >= off) v += y;
    }
    return v;
}

// ---- K2: per-1024-chunk sums of deg, fused with dinv = rsqrt(deg+1)
__global__ __launch_bounds__(256) void block_sums_dinv(const int* __restrict__ deg,
                                                       int* __restrict__ blocksum,
                                                       float* __restrict__ dinv) {
    __shared__ int wsum[4];
    int t = threadIdx.x, lane = t & 63, w = t >> 6;
    int base_i = blockIdx.x * SCAN_CHUNK + t * 4;
    int s = 0;
    #pragma unroll
    for (int j = 0; j < 4; ++j) {
        int i = base_i + j;
        if (i < N_NODES) {
            int dv = deg[i];
            s += dv;
            dinv[i] = rsqrtf((float)dv + 1.0f);
        }
    }
    #pragma unroll
    for (int off = 32; off; off >>= 1) s += __shfl_down(s, off);
    if (lane == 0) wsum[w] = s;
    __syncthreads();
    if (t == 0) blocksum[blockIdx.x] = wsum[0] + wsum[1] + wsum[2] + wsum[3];
}

// ---- K3: parallel exclusive scan of the 98 chunk sums (one block)
__global__ __launch_bounds__(128) void scan_partials(int* __restrict__ bs) {
    __shared__ int w0sum;
    int t = threadIdx.x, lane = t & 63, w = t >> 6;
    int v = (t < N_SCAN_BLOCKS) ? bs[t] : 0;
    int incl = wave_incl_scan(v, lane);
    if (w == 0 && lane == 63) w0sum = incl;
    __syncthreads();
    int ex = incl - v + (w ? w0sum : 0);
    if (t < N_SCAN_BLOCKS) bs[t] = ex;
}

// ---- K4: exclusive scan within each chunk + chunk base -> row_start
__global__ __launch_bounds__(256) void scan_write(const int* __restrict__ deg,
                                                  const int* __restrict__ blockbase,
                                                  int* __restrict__ row_start) {
    __shared__ int wsum[4];
    int t = threadIdx.x, lane = t & 63, w = t >> 6;
    int base_i = blockIdx.x * SCAN_CHUNK + t * 4;
    int v[4]; int s = 0;
    #pragma unroll
    for (int j = 0; j < 4; ++j) {
        int i = base_i + j;
        v[j] = (i < N_NODES) ? deg[i] : 0;
        s += v[j];
    }
    int incl = wave_incl_scan(s, lane);
    int ex = incl - s;
    if (lane == 63) wsum[w] = incl;
    __syncthreads();
    int wbase = 0;
    for (int j = 0; j < w; ++j) wbase += wsum[j];
    int off = blockbase[blockIdx.x] + wbase + ex;
    #pragma unroll
    for (int j = 0; j < 4; ++j) {
        int i = base_i + j;
        if (i < N_NODES) row_start[i] = off;
        off += v[j];
    }
}

// ---- K5: bucket-fill CSR (src index only; norm folded into h')
__global__ void fill_csr(const int* __restrict__ ei, const int* __restrict__ row_start,
                         int* __restrict__ cursor, int* __restrict__ csr) {
    int e = blockIdx.x * blockDim.x + threadIdx.x;
    if (e >= N_EDGES) return;
    int s = ei[e];
    int d = ei[N_EDGES + e];
    int pos = row_start[d] + atomicAdd(&cursor[d], 1);
    csr[pos] = s;
}

// ---- K6: h'[r] = dinv[r] * (x[r] @ W) via bf16 MFMA, stored bf16.
// 512 threads = 8 waves; 128 rows/block (16 rows/wave), full 128 cols.
// W staged transposed+XOR-swizzled in LDS (conflict-free ds_read_b128 B-frags).
__global__ __launch_bounds__(512) void gemm_h_mfma(
        const float* __restrict__ x, const float* __restrict__ W,
        const float* __restrict__ dinv, unsigned short* __restrict__ h) {
    __shared__ unsigned short wt[D * D];  // 32 KB: wt[c][k] bf16, swizzled
    const int tid  = threadIdx.x;
    const int lane = tid & 63;
    const int wv   = tid >> 6;
    const int rb   = blockIdx.x * 128 + wv * 16;

    // A: issue x loads first (HBM-cold, longest latency)
    int arow = rb + (lane & 15);
    if (arow >= N_NODES) arow = N_NODES - 1;
    const float4* xrow = (const float4*)(x + (size_t)arow * D);
    float4 af[8];
    #pragma unroll
    for (int kt = 0; kt < 4; ++kt) {
        int fi = kt * 8 + (lane >> 4) * 2;   // float4 index within row
        af[kt * 2]     = xrow[fi];
        af[kt * 2 + 1] = xrow[fi + 1];
    }

    // W: load 8 float4/thread, cvt, scatter transposed+swizzled into LDS
    const float4* W4 = (const float4*)W;
    float4 wreg[8];
    #pragma unroll
    for (int i = 0; i < 8; ++i) wreg[i] = W4[tid + 512 * i];
    #pragma unroll
    for (int i = 0; i < 8; ++i) {
        int idx = tid + 512 * i;
        int k  = idx >> 5;
        int c0 = (idx & 31) * 4;
        float v[4] = {wreg[i].x, wreg[i].y, wreg[i].z, wreg[i].w};
        #pragma unroll
        for (int j = 0; j < 4; ++j) {
            int c = c0 + j;
            int byte = (c * 256 + k * 2) ^ ((c & 7) << 4);
            *(unsigned short*)((char*)wt + byte) = f2bf(v[j]);
        }
    }
    __syncthreads();

    // cvt A-frags to bf16 (layout: row=l&15, k=(l>>4)*8+j)
    bf16x8 a[4];
    #pragma unroll
    for (int kt = 0; kt < 4; ++kt) {
        float4 u = af[kt * 2], v = af[kt * 2 + 1];
        a[kt][0] = (short)f2bf(u.x); a[kt][1] = (short)f2bf(u.y);
        a[kt][2] = (short)f2bf(u.z); a[kt][3] = (short)f2bf(u.w);
        a[kt][4] = (short)f2bf(v.x); a[kt][5] = (short)f2bf(v.y);
        a[kt][6] = (short)f2bf(v.z); a[kt][7] = (short)f2bf(v.w);
    }

    f32x4 acc[8];
    #pragma unroll
    for (int ct = 0; ct < 8; ++ct) acc[ct] = (f32x4){0.f, 0.f, 0.f, 0.f};

    const int cbase = lane & 15;
    const int kgrp  = (lane >> 4) * 8;
    #pragma unroll
    for (int ct = 0; ct < 8; ++ct) {
        int c = ct * 16 + cbase;
        #pragma unroll
        for (int kt = 0; kt < 4; ++kt) {
            int byte = (c * 256 + (kt * 32 + kgrp) * 2) ^ ((c & 7) << 4);
            bf16x8 b = *(const bf16x8*)((const char*)wt + byte);
            acc[ct] = __builtin_amdgcn_mfma_f32_16x16x32_bf16(a[kt], b, acc[ct], 0, 0, 0);
        }
    }

    // epilogue: scale by dinv[row], cvt bf16, store (D layout: col=l&15, row=(l>>4)*4+q)
    float dq[4]; int orow[4];
    #pragma unroll
    for (int q = 0; q < 4; ++q) {
        orow[q] = rb + (lane >> 4) * 4 + q;
        dq[q] = dinv[orow[q] < N_NODES ? orow[q] : 0];
    }
    #pragma unroll
    for (int ct = 0; ct < 8; ++ct) {
        int col = ct * 16 + (lane & 15);
        #pragma unroll
        for (int q = 0; q < 4; ++q) {
            if (orow[q] < N_NODES)
                h[(size_t)orow[q] * D + col] = f2bf(acc[ct][q] * dq[q]);
        }
    }
}

// ---- K7: out[n] = relu(dinv[n] * (h'[n] + sum_in h'[s]) + b). 32 lanes/node.
__global__ __launch_bounds__(256) void gather_out(const int* __restrict__ csr,
                                                  const int* __restrict__ row_start,
                                                  const int* __restrict__ deg,
                                                  const float* __restrict__ dinv,
                                                  const ushort4* __restrict__ h4,
                                                  const float4* __restrict__ b4,
                                                  float4* __restrict__ out4) {
    int tid = threadIdx.x;
    int c = tid & 31;
    int n = blockIdx.x * 8 + (tid >> 5);
    if (n >= N_NODES) return;
    ushort4 hv = h4[(size_t)n * 32 + c];   // self-loop term
    float4 acc = {bf2f(hv.x), bf2f(hv.y), bf2f(hv.z), bf2f(hv.w)};
    int rs = row_start[n], dg = deg[n];
    for (int base = 0; base < dg; base += 32) {
        int m = min(32, dg - base);
        int src = 0;
        if (c < m) src = csr[rs + base + c];    // 128 B coalesced per chunk
        for (int j = 0; j < m; ++j) {
            int s = __shfl(src, j, 32);
            ushort4 v = h4[(size_t)s * 32 + c]; // 256 B/row, L2/L3-resident
            acc.x += bf2f(v.x); acc.y += bf2f(v.y);
            acc.z += bf2f(v.z); acc.w += bf2f(v.w);
        }
    }
    float di = dinv[n];
    float4 bb = b4[c];
    float4 o;
    o.x = fmaxf(fmaf(di, acc.x, bb.x), 0.f);
    o.y = fmaxf(fmaf(di, acc.y, bb.y), 0.f);
    o.z = fmaxf(fmaf(di, acc.z, bb.z), 0.f);
    o.w = fmaxf(fmaf(di, acc.w, bb.w), 0.f);
    out4[(size_t)n * 32 + c] = o;
}

extern "C" void kernel_launch(void* const* d_in, const int* in_sizes, int n_in,
                              void* d_out, int out_size, void* d_ws, size_t ws_size,
                              hipStream_t stream) {
    const float* x  = (const float*)d_in[0];
    // d_in[1] = x_0 (unused by the reference)
    const float* W  = (const float*)d_in[2];
    const float* b  = (const float*)d_in[3];
    const int*   ei = (const int*)d_in[4];   // [2, N_EDGES]: src then dst
    float* out = (float*)d_out;

    // workspace layout (~34 MB)
    unsigned short* h = (unsigned short*)d_ws;                 // N*D bf16 (25.6 MB)
    int*   deg       = (int*)(h + (size_t)N_NODES * D);
    int*   cursor    = deg + N_NODES;
    float* dinv      = (float*)(cursor + N_NODES);
    int*   row_start = (int*)(dinv + N_NODES);
    int*   blocksum  = row_start + N_NODES;                    // 98 ints
    int*   csr       = blocksum + 128;                         // E ints (6.4 MB)

    hipMemsetAsync(deg, 0, 2 * N_NODES * sizeof(int), stream);  // deg + cursor

    count_deg<<<(N_EDGES + 255) / 256, 256, 0, stream>>>(ei + N_EDGES, deg);
    block_sums_dinv<<<N_SCAN_BLOCKS, 256, 0, stream>>>(deg, blocksum, dinv);
    scan_partials<<<1, 128, 0, stream>>>(blocksum);
    scan_write<<<N_SCAN_BLOCKS, 256, 0, stream>>>(deg, blocksum, row_start);
    fill_csr<<<(N_EDGES + 255) / 256, 256, 0, stream>>>(ei, row_start, cursor, csr);
    gemm_h_mfma<<<(N_NODES + 127) / 128, 512, 0, stream>>>(x, W, dinv, h);
    gather_out<<<(N_NODES + 7) / 8, 256, 0, stream>>>(csr, row_start, deg, dinv,
                                                      (const ushort4*)h,
                                                      (const float4*)b, (float4*)out);
}

// Round 7
// 257.693 us; speedup vs baseline: 11.5544x; 1.4798x over previous
//
#include <hip/hip_runtime.h>

#define N_NODES 100000
#define N_EDGES 1600000
#define D 128
#define G 256                      // nodes per bucket (dst >> 8)
#define NB 391                     // ceil(N_NODES / G)
#define NB_PAD 392
#define CAP 6144                   // bucket capacity (mean 4092, +32 sigma)
#define EPT 16                     // edges per thread in bin_edges

typedef __attribute__((ext_vector_type(8))) short bf16x8;
typedef __attribute__((ext_vector_type(4))) float f32x4;

__device__ inline float bf2f(unsigned short u) {
    return __uint_as_float(((unsigned int)u) << 16);
}
__device__ inline unsigned short f2bf(float f) {  // round-to-nearest-even
    unsigned int u = __float_as_uint(f);
    unsigned int r = u + 0x7FFF + ((u >> 16) & 1);
    return (unsigned short)(r >> 16);
}

__device__ inline int wave_incl_scan(int v, int lane) {
    #pragma unroll
    for (int off = 1; off < 64; off <<= 1) {
        int y = __shfl_up(v, off);
        if (lane >= off) v += y;
    }
    return v;
}

// ---- K1: bin edges by dst>>8. LDS histogram+rank, one global atomic per
// (block,bucket), scatter packed (src | dlocal<<17) into bucket runs.
__global__ __launch_bounds__(256) void bin_edges(const int* __restrict__ ei,
                                                 int* __restrict__ gcursor,
                                                 unsigned int* __restrict__ bins) {
    __shared__ int hist[NB_PAD];
    __shared__ int base[NB_PAD];
    const int tid = threadIdx.x;
    for (int i = tid; i < NB; i += 256) hist[i] = 0;
    __syncthreads();

    const long long e0 = (long long)blockIdx.x * (256 * EPT) + (long long)tid * EPT;
    const bool active = (e0 < N_EDGES);   // N_EDGES % EPT == 0 -> all-or-nothing
    unsigned int packed[EPT]; int bkt[EPT]; int rnk[EPT];
    if (active) {
        const int4* s4 = (const int4*)(ei + e0);
        const int4* d4 = (const int4*)(ei + N_EDGES + e0);
        #pragma unroll
        for (int q = 0; q < EPT / 4; ++q) {
            int4 s = s4[q], d = d4[q];
            int j = q * 4;
            bkt[j+0] = d.x >> 8; packed[j+0] = (unsigned)s.x | ((unsigned)(d.x & 255) << 17);
            bkt[j+1] = d.y >> 8; packed[j+1] = (unsigned)s.y | ((unsigned)(d.y & 255) << 17);
            bkt[j+2] = d.z >> 8; packed[j+2] = (unsigned)s.z | ((unsigned)(d.z & 255) << 17);
            bkt[j+3] = d.w >> 8; packed[j+3] = (unsigned)s.w | ((unsigned)(d.w & 255) << 17);
        }
        #pragma unroll
        for (int j = 0; j < EPT; ++j) rnk[j] = atomicAdd(&hist[bkt[j]], 1);
    }
    __syncthreads();
    for (int i = tid; i < NB; i += 256) {
        int c = hist[i];
        base[i] = c ? atomicAdd(&gcursor[i], c) : 0;
    }
    __syncthreads();
    if (active) {
        #pragma unroll
        for (int j = 0; j < EPT; ++j) {
            int pos = base[bkt[j]] + rnk[j];
            if (pos < CAP) bins[(size_t)bkt[j] * CAP + pos] = packed[j];
        }
    }
}

// ---- K2: exclusive scan of the 391 bucket counts -> bucket edge base
__global__ __launch_bounds__(512) void scan_buckets(const int* __restrict__ gcursor,
                                                    int* __restrict__ bucket_base) {
    __shared__ int wtot[8];
    int t = threadIdx.x, lane = t & 63, w = t >> 6;
    int v = (t < NB) ? gcursor[t] : 0;
    int incl = wave_incl_scan(v, lane);
    if (lane == 63) wtot[w] = incl;
    __syncthreads();
    int add = 0;
    for (int i = 0; i < w; ++i) add += wtot[i];
    if (t < NB) bucket_base[t] = incl - v + add;
}

// ---- K3: per-bucket CSR build fully in LDS: degree hist, scan, scatter,
// coalesced write-out. Also emits deg/dinv/row_start.
__global__ __launch_bounds__(256) void bucket_csr(const unsigned int* __restrict__ bins,
                                                  const int* __restrict__ gcursor,
                                                  const int* __restrict__ bucket_base,
                                                  int* __restrict__ deg,
                                                  float* __restrict__ dinv,
                                                  int* __restrict__ row_start,
                                                  int* __restrict__ csr) {
    __shared__ int degL[G];
    __shared__ int rsL[G];
    __shared__ int curL[G];
    __shared__ int wq[4];
    __shared__ int csrL[CAP];   // 24 KB
    const int b = blockIdx.x, t = threadIdx.x;
    int cb = gcursor[b];
    if (cb > CAP) cb = CAP;
    const int ebase = bucket_base[b];
    degL[t] = 0;
    __syncthreads();
    const unsigned int* mybins = bins + (size_t)b * CAP;
    for (int i = t; i < cb; i += 256)
        atomicAdd(&degL[(mybins[i] >> 17) & 255], 1);
    __syncthreads();
    int v = degL[t];
    int incl = wave_incl_scan(v, t & 63);
    if ((t & 63) == 63) wq[t >> 6] = incl;
    __syncthreads();
    int add = 0;
    for (int i = 0; i < (t >> 6); ++i) add += wq[i];
    int ex = incl - v + add;
    rsL[t] = ex;
    curL[t] = 0;
    int node = b * G + t;
    if (node < N_NODES) {
        deg[node] = v;
        dinv[node] = rsqrtf((float)v + 1.0f);
        row_start[node] = ebase + ex;
    }
    __syncthreads();
    for (int i = t; i < cb; i += 256) {
        unsigned int u = mybins[i];
        int dl = (u >> 17) & 255;
        int pos = rsL[dl] + atomicAdd(&curL[dl], 1);
        csrL[pos] = (int)(u & 0x1FFFF);
    }
    __syncthreads();
    for (int i = t; i < cb; i += 256) csr[ebase + i] = csrL[i];
}

// ---- K4: h'[r] = dinv[r] * (x[r] @ W) via bf16 MFMA, stored bf16.
// 512 threads = 8 waves; 128 rows/block. W transposed+XOR-swizzled in LDS.
__global__ __launch_bounds__(512) void gemm_h_mfma(
        const float* __restrict__ x, const float* __restrict__ W,
        const float* __restrict__ dinv, unsigned short* __restrict__ h) {
    __shared__ unsigned short wt[D * D];  // 32 KB
    const int tid  = threadIdx.x;
    const int lane = tid & 63;
    const int wv   = tid >> 6;
    const int rb   = blockIdx.x * 128 + wv * 16;

    int arow = rb + (lane & 15);
    if (arow >= N_NODES) arow = N_NODES - 1;
    const float4* xrow = (const float4*)(x + (size_t)arow * D);
    float4 af[8];
    #pragma unroll
    for (int kt = 0; kt < 4; ++kt) {
        int fi = kt * 8 + (lane >> 4) * 2;
        af[kt * 2]     = xrow[fi];
        af[kt * 2 + 1] = xrow[fi + 1];
    }

    const float4* W4 = (const float4*)W;
    float4 wreg[8];
    #pragma unroll
    for (int i = 0; i < 8; ++i) wreg[i] = W4[tid + 512 * i];
    #pragma unroll
    for (int i = 0; i < 8; ++i) {
        int idx = tid + 512 * i;
        int k  = idx >> 5;
        int c0 = (idx & 31) * 4;
        float v[4] = {wreg[i].x, wreg[i].y, wreg[i].z, wreg[i].w};
        #pragma unroll
        for (int j = 0; j < 4; ++j) {
            int c = c0 + j;
            int byte = (c * 256 + k * 2) ^ ((c & 7) << 4);
            *(unsigned short*)((char*)wt + byte) = f2bf(v[j]);
        }
    }
    __syncthreads();

    bf16x8 a[4];
    #pragma unroll
    for (int kt = 0; kt < 4; ++kt) {
        float4 u = af[kt * 2], v = af[kt * 2 + 1];
        a[kt][0] = (short)f2bf(u.x); a[kt][1] = (short)f2bf(u.y);
        a[kt][2] = (short)f2bf(u.z); a[kt][3] = (short)f2bf(u.w);
        a[kt][4] = (short)f2bf(v.x); a[kt][5] = (short)f2bf(v.y);
        a[kt][6] = (short)f2bf(v.z); a[kt][7] = (short)f2bf(v.w);
    }

    f32x4 acc[8];
    #pragma unroll
    for (int ct = 0; ct < 8; ++ct) acc[ct] = (f32x4){0.f, 0.f, 0.f, 0.f};

    const int cbase = lane & 15;
    const int kgrp  = (lane >> 4) * 8;
    #pragma unroll
    for (int ct = 0; ct < 8; ++ct) {
        int c = ct * 16 + cbase;
        #pragma unroll
        for (int kt = 0; kt < 4; ++kt) {
            int byte = (c * 256 + (kt * 32 + kgrp) * 2) ^ ((c & 7) << 4);
            bf16x8 bfr = *(const bf16x8*)((const char*)wt + byte);
            acc[ct] = __builtin_amdgcn_mfma_f32_16x16x32_bf16(a[kt], bfr, acc[ct], 0, 0, 0);
        }
    }

    float dq[4]; int orow[4];
    #pragma unroll
    for (int q = 0; q < 4; ++q) {
        orow[q] = rb + (lane >> 4) * 4 + q;
        dq[q] = dinv[orow[q] < N_NODES ? orow[q] : 0];
    }
    #pragma unroll
    for (int ct = 0; ct < 8; ++ct) {
        int col = ct * 16 + (lane & 15);
        #pragma unroll
        for (int q = 0; q < 4; ++q) {
            if (orow[q] < N_NODES)
                h[(size_t)orow[q] * D + col] = f2bf(acc[ct][q] * dq[q]);
        }
    }
}

// ---- K5: out[n] = relu(dinv[n] * (h'[n] + sum_in h'[s]) + b). 32 lanes/node.
__global__ __launch_bounds__(256) void gather_out(const int* __restrict__ csr,
                                                  const int* __restrict__ row_start,
                                                  const int* __restrict__ deg,
                                                  const float* __restrict__ dinv,
                                                  const ushort4* __restrict__ h4,
                                                  const float4* __restrict__ b4,
                                                  float4* __restrict__ out4) {
    int tid = threadIdx.x;
    int c = tid & 31;
    int n = blockIdx.x * 8 + (tid >> 5);
    if (n >= N_NODES) return;
    ushort4 hv = h4[(size_t)n * 32 + c];   // self-loop term
    float4 acc = {bf2f(hv.x), bf2f(hv.y), bf2f(hv.z), bf2f(hv.w)};
    int rs = row_start[n], dg = deg[n];
    for (int base = 0; base < dg; base += 32) {
        int m = min(32, dg - base);
        int src = 0;
        if (c < m) src = csr[rs + base + c];
        for (int j = 0; j < m; ++j) {
            int s = __shfl(src, j, 32);
            ushort4 v = h4[(size_t)s * 32 + c];
            acc.x += bf2f(v.x); acc.y += bf2f(v.y);
            acc.z += bf2f(v.z); acc.w += bf2f(v.w);
        }
    }
    float di = dinv[n];
    float4 bb = b4[c];
    float4 o;
    o.x = fmaxf(fmaf(di, acc.x, bb.x), 0.f);
    o.y = fmaxf(fmaf(di, acc.y, bb.y), 0.f);
    o.z = fmaxf(fmaf(di, acc.z, bb.z), 0.f);
    o.w = fmaxf(fmaf(di, acc.w, bb.w), 0.f);
    out4[(size_t)n * 32 + c] = o;
}

extern "C" void kernel_launch(void* const* d_in, const int* in_sizes, int n_in,
                              void* d_out, int out_size, void* d_ws, size_t ws_size,
                              hipStream_t stream) {
    const float* x  = (const float*)d_in[0];
    // d_in[1] = x_0 (unused by the reference)
    const float* W  = (const float*)d_in[2];
    const float* b  = (const float*)d_in[3];
    const int*   ei = (const int*)d_in[4];   // [2, N_EDGES]: src then dst
    float* out = (float*)d_out;

    // workspace layout (~43 MB)
    unsigned short* h = (unsigned short*)d_ws;                // N*D bf16 (25.6 MB)
    int*   deg         = (int*)(h + (size_t)N_NODES * D);     // N
    float* dinv        = (float*)(deg + N_NODES);             // N
    int*   row_start   = (int*)(dinv + N_NODES);              // N
    int*   gcursor     = row_start + N_NODES;                 // NB_PAD
    int*   bucket_base = gcursor + NB_PAD;                    // NB_PAD
    int*   csr         = bucket_base + NB_PAD;                // E (6.4 MB)
    unsigned int* bins = (unsigned int*)(csr + N_EDGES);      // NB*CAP (9.6 MB)

    hipMemsetAsync(gcursor, 0, NB_PAD * sizeof(int), stream);

    bin_edges<<<(N_EDGES + 256 * EPT - 1) / (256 * EPT), 256, 0, stream>>>(ei, gcursor, bins);
    scan_buckets<<<1, 512, 0, stream>>>(gcursor, bucket_base);
    bucket_csr<<<NB, 256, 0, stream>>>(bins, gcursor, bucket_base, deg, dinv, row_start, csr);
    gemm_h_mfma<<<(N_NODES + 127) / 128, 512, 0, stream>>>(x, W, dinv, h);
    gather_out<<<(N_NODES + 7) / 8, 256, 0, stream>>>(csr, row_start, deg, dinv,
                                                      (const ushort4*)h,
                                                      (const float4*)b, (float4*)out);
}